// Round 9
// baseline (665.090 us; speedup 1.0000x reference)
//
#include <hip/hip_runtime.h>
#include <hip/hip_fp16.h>
#include <math.h>

#define SPB 8           // samples per block: 256 threads, 32 lanes per sample
#define TOL2 1e-5f      // (gamma^2)/(alpha*beta) threshold, tau ~= 3e-3

typedef float v2f __attribute__((ext_vector_type(2)));

__device__ __forceinline__ float bperm(int srcidx, float x) {
    return __int_as_float(__builtin_amdgcn_ds_bpermute(srcidx, __float_as_int(x)));
}
template <int CTRL>
__device__ __forceinline__ float dppx(float x) {
    return __int_as_float(__builtin_amdgcn_mov_dpp(__float_as_int(x), CTRL, 0xF, 0xF, true));
}
template <int MASK>
__device__ __forceinline__ float swzf(float x) {   // XOR swizzle within 32-lane groups
    return __int_as_float(__builtin_amdgcn_ds_swizzle(__float_as_int(x), (MASK << 10) | 0x1F));
}
__device__ __forceinline__ float frcp(float x)  { return __builtin_amdgcn_rcpf(x); }
__device__ __forceinline__ float fsq(float x)   { return __builtin_amdgcn_sqrtf(x); }
__device__ __forceinline__ float frsq(float x)  { return __builtin_amdgcn_rsqf(x); }

// DPP ctrl: quad_perm XOR1=0xB1 XOR2=0x4E XOR3=0x1B,
// ROW_HALF_MIRROR(X7)=0x141, ROW_ROR:8(X8)=0x128, ROW_MIRROR(X15)=0x140
#define DPP_X1 0xB1
#define DPP_X2 0x4E
#define DPP_X3 0x1B
#define DPP_X7 0x141
#define DPP_X8 0x128
#define DPP_X15 0x140

// Scaled Jacobi rotation, packed-f32 inner loops. Column stored as d*ahat in
// 16 VGPR pairs; update is 16 v_pk_fma. Both lanes of a pair derive
// bit-identical rotation params (only commutative/antisymmetric shared terms).
__device__ __forceinline__ void jstep(v2f (&a)[16], float& n, float& d, float& rd,
                                      v2f (&b)[16], float nb, float db,
                                      float hw, unsigned sgn, bool& anyrot)
{
    // pin partner column (blocks rematerialization of the fetch ops)
    #pragma unroll
    for (int k = 0; k < 16; ++k) asm("" : "+v"(b[k]));

    v2f acc0 = {0.f, 0.f}, acc1 = {0.f, 0.f};
    #pragma unroll
    for (int k = 0; k < 16; k += 2) {
        asm("v_pk_fma_f32 %0, %1, %2, %0" : "+v"(acc0) : "v"(a[k]),   "v"(b[k]));
        asm("v_pk_fma_f32 %0, %1, %2, %0" : "+v"(acc1) : "v"(a[k+1]), "v"(b[k+1]));
    }
    float gh = (acc0.x + acc0.y) + (acc1.x + acc1.y);
    float gamma = (d * db) * gh;            // true gamma (pair-symmetric)
    float ab  = n * nb;
    float g2s = gamma * gamma;
    bool dorot = g2s > TOL2 * ab;
    if (__ballot(dorot) == 0ull) return;    // wave-uniform skip (verification sweeps)
    anyrot = true;

    // w = (zh-zl)/2, identical bits on both lanes; t = sign(w)*g/(|w|+sqrt(w^2+g^2))
    float w   = (nb - n) * hw;
    float hyp = fsq(fmaf(w, w, g2s));
    float tt  = gamma * copysignf(frcp(fabsf(w) + hyp), w);
    tt = dorot ? tt : 0.f;
    float u  = fmaf(tt, tt, 1.f);           // 1/cos^2
    float te = __int_as_float(__float_as_int(tt) ^ sgn);  // lo: -t, hi: +t
    float m  = (te * db) * rd;
    v2f mm = {m, m};
    #pragma unroll
    for (int k = 0; k < 16; ++k)
        asm("v_pk_fma_f32 %0, %1, %2, %0" : "+v"(a[k]) : "v"(mm), "v"(b[k]));
    n  = fmaf(te, gamma, n);
    d  = d * frsq(u);                       // parallel rsqrt/sqrt (no serial rcp)
    rd = rd * fsq(u);
}

template <int CTRL>
__device__ __forceinline__ void step_dpp(v2f (&a)[16], float& n, float& d, float& rd,
                                         float hw, unsigned sgn, bool& anyrot)
{
    v2f b[16];
    #pragma unroll
    for (int k = 0; k < 16; ++k) { b[k].x = dppx<CTRL>(a[k].x); b[k].y = dppx<CTRL>(a[k].y); }
    float nb = dppx<CTRL>(n);
    float db = dppx<CTRL>(d);
    jstep(a, n, d, rd, b, nb, db, hw, sgn, anyrot);
}
// double-DPP fetch: partner = dpp<C2>(dpp<C1>(x)), XOR mask = X(C1)^X(C2)
template <int C1, int C2>
__device__ __forceinline__ void step_dpp2(v2f (&a)[16], float& n, float& d, float& rd,
                                          float hw, unsigned sgn, bool& anyrot)
{
    v2f b[16];
    #pragma unroll
    for (int k = 0; k < 16; ++k) {
        b[k].x = dppx<C2>(dppx<C1>(a[k].x));
        b[k].y = dppx<C2>(dppx<C1>(a[k].y));
    }
    float nb = dppx<C2>(dppx<C1>(n));
    float db = dppx<C2>(dppx<C1>(d));
    jstep(a, n, d, rd, b, nb, db, hw, sgn, anyrot);
}
template <int MASK>
__device__ __forceinline__ void step_swz(v2f (&a)[16], float& n, float& d, float& rd,
                                         float hw, unsigned sgn, bool& anyrot)
{
    v2f b[16];
    #pragma unroll
    for (int k = 0; k < 16; ++k) { b[k].x = swzf<MASK>(a[k].x); b[k].y = swzf<MASK>(a[k].y); }
    float nb = swzf<MASK>(n);
    float db = swzf<MASK>(d);
    jstep(a, n, d, rd, b, nb, db, hw, sgn, anyrot);
}

__device__ __forceinline__ v2f up2(unsigned int w) {
    __half2 h = *reinterpret_cast<__half2*>(&w);
    float2 f = __half22float2(h);
    v2f r; r.x = f.x; r.y = f.y;
    return r;
}

#define STEP_DPP(CTRL, BIT) do { bool lo_ = (lane32 & (BIT)) == 0; \
    step_dpp<CTRL>(a, n, d, rd, lo_ ? 0.5f : -0.5f, lo_ ? 0x80000000u : 0u, anyrot); } while (0)
#define STEP_DPP2(CA, CB, BIT) do { bool lo_ = (lane32 & (BIT)) == 0; \
    step_dpp2<CA, CB>(a, n, d, rd, lo_ ? 0.5f : -0.5f, lo_ ? 0x80000000u : 0u, anyrot); } while (0)
#define STEP_SWZ(M, BIT) do { bool lo_ = (lane32 & (BIT)) == 0; \
    step_swz<M>(a, n, d, rd, lo_ ? 0.5f : -0.5f, lo_ ? 0x80000000u : 0u, anyrot); } while (0)

__global__ __launch_bounds__(256, 3)
void geodesic_loss_kernel(const float* __restrict__ yhat,
                          const float* __restrict__ y,
                          float* __restrict__ out, int B)
{
    __shared__ unsigned short G1[SPB][32][32];   // f16 ghat1 (16 KB)
    __shared__ float bl[SPB];

    const int t      = threadIdx.x;
    const int slot   = t >> 5;
    const int lane32 = t & 31;
    const int lane64 = t & 63;

    int b = blockIdx.x * SPB + slot;
    const float valid = (b < B) ? 1.f : 0.f;
    if (b >= B) b = B - 1;

    v2f a[16];                    // scaled column (true column = d * a)
    float diagAcc = 0.f;
    float S = 0.f;

    #pragma unroll 1
    for (int phase = 0; phase < 2; ++phase) {
        const float* A = (phase == 0 ? yhat : y) + ((size_t)b << 10) + (lane32 << 5);
        #pragma unroll
        for (int c = 0; c < 8; ++c) {
            float4 v = reinterpret_cast<const float4*>(A)[c];
            a[2*c+0].x = v.x; a[2*c+0].y = v.y;
            a[2*c+1].x = v.z; a[2*c+1].y = v.w;
        }
        v2f nacc0 = {0.f, 0.f}, nacc1 = {0.f, 0.f};
        #pragma unroll
        for (int k = 0; k < 16; k += 2) {
            asm("v_pk_fma_f32 %0, %1, %1, %0" : "+v"(nacc0) : "v"(a[k]));
            asm("v_pk_fma_f32 %0, %1, %1, %0" : "+v"(nacc1) : "v"(a[k+1]));
        }
        float n = (nacc0.x + nacc0.y) + (nacc1.x + nacc1.y);
        float d = 1.f, rd = 1.f;

        #pragma unroll 1
        for (int sweep = 0; sweep < 10; ++sweep) {
            bool anyrot = false;

            // masks 1..15 on the VALU pipe: singles + double-DPP composites
            STEP_DPP(DPP_X1, 1);                 // 1
            STEP_DPP(DPP_X2, 2);                 // 2
            STEP_DPP(DPP_X3, 2);                 // 3
            STEP_DPP2(DPP_X7, DPP_X3, 4);        // 4 = 7^3
            STEP_DPP2(DPP_X7, DPP_X2, 4);        // 5 = 7^2
            STEP_DPP2(DPP_X7, DPP_X1, 4);        // 6 = 7^1
            STEP_DPP(DPP_X7, 4);                 // 7
            STEP_DPP(DPP_X8, 8);                 // 8
            STEP_DPP2(DPP_X8, DPP_X1, 8);        // 9
            STEP_DPP2(DPP_X8, DPP_X2, 8);        // 10
            STEP_DPP2(DPP_X8, DPP_X3, 8);        // 11
            STEP_DPP2(DPP_X15, DPP_X3, 8);       // 12 = 15^3
            STEP_DPP2(DPP_X15, DPP_X2, 8);       // 13 = 15^2
            STEP_DPP2(DPP_X15, DPP_X1, 8);       // 14 = 15^1
            STEP_DPP(DPP_X15, 8);                // 15
            // masks 16..31 on the DS pipe (ds_swizzle, compile-time pattern)
            STEP_SWZ(16, 16);  STEP_SWZ(17, 16);  STEP_SWZ(18, 16);  STEP_SWZ(19, 16);
            STEP_SWZ(20, 16);  STEP_SWZ(21, 16);  STEP_SWZ(22, 16);  STEP_SWZ(23, 16);
            STEP_SWZ(24, 16);  STEP_SWZ(25, 16);  STEP_SWZ(26, 16);  STEP_SWZ(27, 16);
            STEP_SWZ(28, 16);  STEP_SWZ(29, 16);  STEP_SWZ(30, 16);  STEP_SWZ(31, 16);

            if (!anyrot) break;             // d == 1 here, nothing to fold

            v2f dd2 = {d, d};               // fold scale back into column
            #pragma unroll
            for (int k = 0; k < 16; ++k)
                asm("v_pk_mul_f32 %0, %0, %1" : "+v"(a[k]) : "v"(dd2));
            d = 1.f; rd = 1.f;
        }

        // eigenvalue = fresh final column norm
        v2f lacc0 = {0.f, 0.f}, lacc1 = {0.f, 0.f};
        #pragma unroll
        for (int k = 0; k < 16; k += 2) {
            asm("v_pk_fma_f32 %0, %1, %1, %0" : "+v"(lacc0) : "v"(a[k]));
            asm("v_pk_fma_f32 %0, %1, %1, %0" : "+v"(lacc1) : "v"(a[k+1]));
        }
        float lam2 = (lacc0.x + lacc0.y) + (lacc1.x + lacc1.y);
        float ll = 0.5f * logf(lam2);             // >= 0 (SPD, eig >= 1)
        diagAcc = fmaf(ll, ll, diagAcc);
        float sc = sqrtf(fmaxf(ll, 0.f) / lam2);  // sqrt(log l)/l folded in
        v2f sc2 = {sc, sc};
        #pragma unroll
        for (int k = 0; k < 16; ++k)
            asm("v_pk_mul_f32 %0, %0, %1" : "+v"(a[k]) : "v"(sc2));

        if (phase == 0) {
            // pack scaled column to f16, store 4x uint4 (same wave reads back
            // in phase 1 -> no barrier needed)
            unsigned int hw[16];
            #pragma unroll
            for (int k = 0; k < 16; ++k) {
                unsigned int lo = __half_as_ushort(__float2half(a[k].x));
                unsigned int hi = __half_as_ushort(__float2half(a[k].y));
                hw[k] = lo | (hi << 16);
            }
            uint4* rp = reinterpret_cast<uint4*>(&G1[slot][lane32][0]);
            #pragma unroll
            for (int c = 0; c < 4; ++c)
                rp[c] = make_uint4(hw[4*c+0], hw[4*c+1], hw[4*c+2], hw[4*c+3]);
        } else {
            // S_j = sum_i (ghat1_i . ghat2_j)^2 ; broadcast reads (conflict-free)
            for (int i = 0; i < 32; ++i) {
                const uint4* colp = reinterpret_cast<const uint4*>(&G1[slot][i][0]);
                v2f dacc0 = {0.f, 0.f}, dacc1 = {0.f, 0.f};
                #pragma unroll
                for (int c = 0; c < 4; ++c) {
                    uint4 wv = colp[c];
                    v2f f0 = up2(wv.x), f1 = up2(wv.y), f2 = up2(wv.z), f3 = up2(wv.w);
                    asm("v_pk_fma_f32 %0, %1, %2, %0" : "+v"(dacc0) : "v"(f0), "v"(a[4*c+0]));
                    asm("v_pk_fma_f32 %0, %1, %2, %0" : "+v"(dacc1) : "v"(f1), "v"(a[4*c+1]));
                    asm("v_pk_fma_f32 %0, %1, %2, %0" : "+v"(dacc0) : "v"(f2), "v"(a[4*c+2]));
                    asm("v_pk_fma_f32 %0, %1, %2, %0" : "+v"(dacc1) : "v"(f3), "v"(a[4*c+3]));
                }
                float dd = (dacc0.x + dacc0.y) + (dacc1.x + dacc1.y);
                S = fmaf(dd, dd, S);
            }
        }
    }

    // tr(D^2) partial per lane, reduce over the 32 lanes of this sample
    float p = fmaf(-2.f, S, diagAcc);
    #pragma unroll
    for (int m = 16; m >= 1; m >>= 1)
        p += bperm(((lane64 ^ m) << 2), p);
    if (lane32 == 0) bl[slot] = valid * sqrtf(fmaxf(p, 0.f));
    __syncthreads();
    if (t == 0) {
        float sum = 0.f;
        #pragma unroll
        for (int i = 0; i < SPB; ++i) sum += bl[i];
        atomicAdd(out, sum);
    }
}

extern "C" void kernel_launch(void* const* d_in, const int* in_sizes, int n_in,
                              void* d_out, int out_size, void* d_ws, size_t ws_size,
                              hipStream_t stream)
{
    const float* yhat = (const float*)d_in[0];
    const float* y    = (const float*)d_in[1];
    float* out = (float*)d_out;
    const int B = in_sizes[0] / 1024;   // 32*32 per matrix

    (void)hipMemsetAsync(out, 0, sizeof(float), stream);
    const int grid = (B + SPB - 1) / SPB;
    hipLaunchKernelGGL(geodesic_loss_kernel, dim3(grid), dim3(256), 0, stream,
                       yhat, y, out, B);
}

// Round 11
// 451.214 us; speedup vs baseline: 1.4740x; 1.4740x over previous
//
#include <hip/hip_runtime.h>
#include <math.h>

#define NW 4   // waves (=samples) per 256-thread block

typedef __attribute__((ext_vector_type(8)))  short bf16x8;
typedef __attribute__((ext_vector_type(16))) float f32x16;

__device__ __forceinline__ float bperm(int srcidx, float x) {
    return __int_as_float(__builtin_amdgcn_ds_bpermute(srcidx, __float_as_int(x)));
}
// f32 -> bf16 bits, round-to-nearest-even
__device__ __forceinline__ unsigned f2bfu(float x) {
    unsigned u = __float_as_uint(x);
    return (u + 0x7fffu + ((u >> 16) & 1u)) >> 16;
}
__device__ __forceinline__ float bf2f(unsigned hbits) {
    return __uint_as_float(hbits << 16);
}

// logm via deg-12 Chebyshev of log on [1,8]: S=(M-4.5I)/3.5, T_{k+1}=2ST_k-T_{k-1}.
// MFMA 32x32x16 bf16, hi/lo split. ALL layout facts (A/B slot pairing, C reg->row,
// C lane->col) are DISCOVERED at runtime by 3 one-MFMA probes; symmetric matrices +
// commuting polynomial products make every remaining convention harmless.
__global__ __launch_bounds__(256, 2)
void geo_loss_mfma(const float* __restrict__ yhat, const float* __restrict__ y,
                   float* __restrict__ out, int B)
{
    __shared__ float lds[NW][32][36];
    __shared__ float bl[NW];

    const int t    = threadIdx.x;
    const int w    = t >> 6;
    const int lane = t & 63;
    const int c    = lane & 31;
    const int h    = lane >> 5;

    int b = blockIdx.x * NW + w;
    const float valid = (b < B) ? 1.f : 0.f;
    if (b >= B) b = B - 1;

    const f32x16 zz = {0.f,0.f,0.f,0.f,0.f,0.f,0.f,0.f,0.f,0.f,0.f,0.f,0.f,0.f,0.f,0.f};
    float sent = 0.f;

    // ---- probe 1: relative A/B slot-labeling delta (6 hypotheses) ----
    bf16x8 pa;
    #pragma unroll
    for (int j = 0; j < 8; ++j) pa[j] = (short)f2bfu((float)(8*h + j + 1));
    int sel = -1;
    #pragma unroll
    for (int cand = 0; cand < 6; ++cand) {
        const int hf = cand & 1, jmc = cand >> 1;
        bf16x8 pb;
        #pragma unroll
        for (int j = 0; j < 8; ++j) {
            int hh = hf ? (1 - h) : h;
            int jj = (jmc == 0) ? j : (jmc == 1 ? (j ^ 4) : (7 - j));
            float lab = (float)(8*hh + jj + 1);
            pb[j] = (short)f2bfu(lab * lab);
        }
        f32x16 pr = __builtin_amdgcn_mfma_f32_32x32x16_bf16(pa, pb, zz, 0, 0, 0);
        if (sel < 0 && __ballot(pr[0] != 18496.f) == 0ull) sel = cand;  // sum m^3, m=1..16
    }
    if (sel < 0) { sent += 1.0e10f; sel = 0; }
    const int hf = sel & 1, jm = sel >> 1;

    // ---- probe 2: C (lane,reg) -> row map.  A=c+1 (const/lane), B=1 ----
    bf16x8 pa2, pb1;
    #pragma unroll
    for (int j = 0; j < 8; ++j) {
        pa2[j] = (short)f2bfu((float)(c + 1));
        pb1[j] = (short)f2bfu(1.f);
    }
    f32x16 r2 = __builtin_amdgcn_mfma_f32_32x32x16_bf16(pa2, pb1, zz, 0, 0, 0);
    int rws[16]; bool ok2 = true;
    #pragma unroll
    for (int i = 0; i < 16; ++i) {
        float q = r2[i] * 0.0625f;
        int ri = (int)(q + 0.5f);
        ok2 = ok2 && (fabsf(q - (float)ri) < 1e-3f) && ri >= 1 && ri <= 32;
        rws[i] = ri - 1;
    }
    if (__ballot(!ok2) != 0ull) {
        sent += 2.0e10f;
        #pragma unroll
        for (int i = 0; i < 16; ++i) rws[i] = (i & 3) + 8*(i >> 2) + 4*h;
    }

    // ---- probe 3: C lane -> col map.  A=1, B=c+1 ----
    f32x16 r3 = __builtin_amdgcn_mfma_f32_32x32x16_bf16(pb1, pa2, zz, 0, 0, 0);
    int colstar;
    {
        float q = r3[0] * 0.0625f;
        int ci = (int)(q + 0.5f);
        bool ok3 = (fabsf(q - (float)ci) < 1e-3f) && ci >= 1 && ci <= 32;
        colstar = ci - 1;
        if (__ballot(!ok3) != 0ull) { sent += 4.0e10f; colstar = c; }
    }
    if (lane == 0 && sent > 0.f) atomicAdd(out, sent);

    const float INV = 0.2857142857142857f;   // 1/3.5
    float* slabW       = &lds[w][colstar][0];   // store: this lane's C column
    const float* slabR = &lds[w][c][0];         // read:  B operand column for this lane
    const int kb = (hf ? (1 - h) : h) * 8;      // delta: half-lane flip on B reads

    float PA[16];

    #pragma unroll 1
    for (int phase = 0; phase < 2; ++phase) {
        const float* Mp = (phase == 0 ? yhat : y) + ((size_t)b << 10);

        // ---- A-fragments of S (bf16 hi/lo), my labeling k=8h+j (+16) ----
        bf16x8 Ah0, Al0, Ah1, Al1;
        {
            const float4* p = reinterpret_cast<const float4*>(Mp + c*32 + 8*h);
            float4 q0 = p[0], q1 = p[1];
            float fv[8] = {q0.x,q0.y,q0.z,q0.w, q1.x,q1.y,q1.z,q1.w};
            #pragma unroll
            for (int j = 0; j < 8; ++j) {
                int k = 8*h + j;
                float x = (fv[j] - ((k == c) ? 4.5f : 0.f)) * INV;
                unsigned hi = f2bfu(x);
                Ah0[j] = (short)hi; Al0[j] = (short)f2bfu(x - bf2f(hi));
            }
        }
        {
            const float4* p = reinterpret_cast<const float4*>(Mp + c*32 + 16 + 8*h);
            float4 q0 = p[0], q1 = p[1];
            float fv[8] = {q0.x,q0.y,q0.z,q0.w, q1.x,q1.y,q1.z,q1.w};
            #pragma unroll
            for (int j = 0; j < 8; ++j) {
                int k = 16 + 8*h + j;
                float x = (fv[j] - ((k == c) ? 4.5f : 0.f)) * INV;
                unsigned hi = f2bfu(x);
                Ah1[j] = (short)hi; Al1[j] = (short)f2bfu(x - bf2f(hi));
            }
        }

        // ---- V = T1 = S in C-space (discovered positions); U = T0 = I ----
        float U[16], V[16], P[16];
        #pragma unroll
        for (int i = 0; i < 16; ++i) {
            float dg = (rws[i] == colstar) ? 1.f : 0.f;
            float mv = Mp[colstar * 32 + rws[i]];           // M symmetric
            V[i] = (mv - 4.5f * dg) * INV;
            U[i] = dg;
            P[i] = fmaf(0.95518452f, V[i], 1.2986135f * dg); // c1*T1 + c0*I
        }
        #pragma unroll
        for (int i = 0; i < 16; ++i) slabW[rws[i]] = V[i];   // LDS holds T1

        // B-read with delta j-permutation (wave-uniform jm), hi/lo convert
        auto CVT8 = [&](const float* src, bf16x8& Bh, bf16x8& Bl) {
            float4 v0 = *reinterpret_cast<const float4*>(src);
            float4 v1 = *reinterpret_cast<const float4*>(src + 4);
            float f[8] = {v0.x,v0.y,v0.z,v0.w, v1.x,v1.y,v1.z,v1.w};
            if (jm == 0) {
                #pragma unroll
                for (int j = 0; j < 8; ++j) { float x = f[j];
                    unsigned hi = f2bfu(x); Bh[j]=(short)hi; Bl[j]=(short)f2bfu(x-bf2f(hi)); }
            } else if (jm == 1) {
                #pragma unroll
                for (int j = 0; j < 8; ++j) { float x = f[j ^ 4];
                    unsigned hi = f2bfu(x); Bh[j]=(short)hi; Bl[j]=(short)f2bfu(x-bf2f(hi)); }
            } else {
                #pragma unroll
                for (int j = 0; j < 8; ++j) { float x = f[7 - j];
                    unsigned hi = f2bfu(x); Bh[j]=(short)hi; Bl[j]=(short)f2bfu(x-bf2f(hi)); }
            }
        };

        // one Chebyshev step: LDS holds T_k; W held T_{k-1}; W <- 2*S*T_k - W
        auto STEP = [&](float coef, float (&W)[16], bool dostore) {
            bf16x8 Bh0, Bl0, Bh1, Bl1;
            CVT8(slabR + kb,      Bh0, Bl0);
            CVT8(slabR + 16 + kb, Bh1, Bl1);
            f32x16 a2 = zz;
            a2 = __builtin_amdgcn_mfma_f32_32x32x16_bf16(Ah0, Bh0, a2, 0,0,0);
            a2 = __builtin_amdgcn_mfma_f32_32x32x16_bf16(Ah0, Bl0, a2, 0,0,0);
            a2 = __builtin_amdgcn_mfma_f32_32x32x16_bf16(Al0, Bh0, a2, 0,0,0);
            a2 = __builtin_amdgcn_mfma_f32_32x32x16_bf16(Ah1, Bh1, a2, 0,0,0);
            a2 = __builtin_amdgcn_mfma_f32_32x32x16_bf16(Ah1, Bl1, a2, 0,0,0);
            a2 = __builtin_amdgcn_mfma_f32_32x32x16_bf16(Al1, Bh1, a2, 0,0,0);
            #pragma unroll
            for (int i = 0; i < 16; ++i) {
                float nw = 2.f * a2[i] - W[i];
                nw = fminf(fmaxf(nw, -64.f), 64.f);   // never binds when correct
                W[i] = nw;
                P[i] = fmaf(coef, nw, P[i]);
            }
            if (dostore) {
                #pragma unroll
                for (int i = 0; i < 16; ++i) slabW[rws[i]] = W[i];
            }
        };

        STEP(-0.22809412f, U, true);    // T2
        STEP( 0.07262391f, V, true);    // T3
        STEP(-0.02601347f, U, true);    // T4
        STEP( 0.00993906f, V, true);    // T5
        STEP(-0.00395568f, U, true);    // T6
        STEP( 0.00161931f, V, true);    // T7
        STEP(-0.00067670f, U, true);    // T8
        STEP( 0.00028728f, V, true);    // T9
        STEP(-0.00012348f, U, true);    // T10
        STEP( 0.00005361f, V, true);    // T11
        STEP(-0.00002347f, U, false);   // T12

        if (phase == 0) {
            #pragma unroll
            for (int i = 0; i < 16; ++i) PA[i] = P[i];
        } else {
            float s = 0.f;
            #pragma unroll
            for (int i = 0; i < 16; ++i) { float d = PA[i] - P[i]; s = fmaf(d, d, s); }
            #pragma unroll
            for (int m = 32; m >= 1; m >>= 1)
                s += bperm((lane ^ m) << 2, s);       // position-independent full sum
            if (lane == 0) bl[w] = valid * sqrtf(fmaxf(s, 0.f));
        }
    }

    __syncthreads();
    if (t == 0) {
        float sum = 0.f;
        #pragma unroll
        for (int i = 0; i < NW; ++i) sum += bl[i];
        atomicAdd(out, sum);
    }
}

extern "C" void kernel_launch(void* const* d_in, const int* in_sizes, int n_in,
                              void* d_out, int out_size, void* d_ws, size_t ws_size,
                              hipStream_t stream)
{
    const float* yhat = (const float*)d_in[0];
    const float* y    = (const float*)d_in[1];
    float* out = (float*)d_out;
    const int B = in_sizes[0] / 1024;   // 32*32 per matrix

    (void)hipMemsetAsync(out, 0, sizeof(float), stream);
    const int grid = (B + NW - 1) / NW;
    hipLaunchKernelGGL(geo_loss_mfma, dim3(grid), dim3(256), 0, stream,
                       yhat, y, out, B);
}

// Round 12
// 263.190 us; speedup vs baseline: 2.5270x; 1.7144x over previous
//
#include <hip/hip_runtime.h>
#include <math.h>

#define NW 4   // waves (=samples) per 256-thread block

typedef __attribute__((ext_vector_type(8)))  short bf16x8;
typedef __attribute__((ext_vector_type(16))) float f32x16;

__device__ __forceinline__ float bperm(int srcidx, float x) {
    return __int_as_float(__builtin_amdgcn_ds_bpermute(srcidx, __float_as_int(x)));
}
// f32 -> bf16 bits, round-to-nearest-even
__device__ __forceinline__ unsigned f2bfu(float x) {
    unsigned u = __float_as_uint(x);
    return (u + 0x7fffu + ((u >> 16) & 1u)) >> 16;
}
__device__ __forceinline__ float bf2f(unsigned hbits) {
    return __uint_as_float(hbits << 16);
}

// logm via deg-12 Chebyshev of log on [1,8]: S=(M-4.5I)/3.5, T_{k+1}=2ST_k-T_{k-1}.
// MFMA 32x32x16 bf16, hi/lo split. Layout facts discovered by 3 one-MFMA probes
// (R10: verified working, absmax 0.0). R11: spill elimination — launch_bounds(256,1),
// PA in LDS, S staged to LDS from the A-frag load (symmetry) instead of re-reading HBM.
__global__ __launch_bounds__(256, 1)
void geo_loss_mfma(const float* __restrict__ yhat, const float* __restrict__ y,
                   float* __restrict__ out, int B)
{
    __shared__ float lds[NW][32][36];    // per-wave T_k columns (pad 36)
    __shared__ float pbuf[NW][64][17];   // P_A stash (pad 17: conflict-free)
    __shared__ float bl[NW];

    const int t    = threadIdx.x;
    const int w    = t >> 6;
    const int lane = t & 63;
    const int c    = lane & 31;
    const int h    = lane >> 5;

    int b = blockIdx.x * NW + w;
    const float valid = (b < B) ? 1.f : 0.f;
    if (b >= B) b = B - 1;

    const f32x16 zz = {0.f,0.f,0.f,0.f,0.f,0.f,0.f,0.f,0.f,0.f,0.f,0.f,0.f,0.f,0.f,0.f};
    float sent = 0.f;

    // ---- probe 1: relative A/B slot-labeling delta (6 hypotheses) ----
    bf16x8 pa;
    #pragma unroll
    for (int j = 0; j < 8; ++j) pa[j] = (short)f2bfu((float)(8*h + j + 1));
    int sel = -1;
    #pragma unroll
    for (int cand = 0; cand < 6; ++cand) {
        const int hfc = cand & 1, jmc = cand >> 1;
        bf16x8 pb;
        #pragma unroll
        for (int j = 0; j < 8; ++j) {
            int hh = hfc ? (1 - h) : h;
            int jj = (jmc == 0) ? j : (jmc == 1 ? (j ^ 4) : (7 - j));
            float lab = (float)(8*hh + jj + 1);
            pb[j] = (short)f2bfu(lab * lab);
        }
        f32x16 pr = __builtin_amdgcn_mfma_f32_32x32x16_bf16(pa, pb, zz, 0, 0, 0);
        if (sel < 0 && __ballot(pr[0] != 18496.f) == 0ull) sel = cand;  // sum m^3, m=1..16
    }
    if (sel < 0) { sent += 1.0e10f; sel = 0; }
    const int hf = sel & 1, jm = sel >> 1;

    // ---- probe 2: C (lane,reg) -> row map.  A=c+1 (const/lane), B=1 ----
    bf16x8 pa2, pb1;
    #pragma unroll
    for (int j = 0; j < 8; ++j) {
        pa2[j] = (short)f2bfu((float)(c + 1));
        pb1[j] = (short)f2bfu(1.f);
    }
    f32x16 r2 = __builtin_amdgcn_mfma_f32_32x32x16_bf16(pa2, pb1, zz, 0, 0, 0);
    int rws[16]; bool ok2 = true;
    #pragma unroll
    for (int i = 0; i < 16; ++i) {
        float q = r2[i] * 0.0625f;
        int ri = (int)(q + 0.5f);
        ok2 = ok2 && (fabsf(q - (float)ri) < 1e-3f) && ri >= 1 && ri <= 32;
        rws[i] = ri - 1;
    }
    if (__ballot(!ok2) != 0ull) {
        sent += 2.0e10f;
        #pragma unroll
        for (int i = 0; i < 16; ++i) rws[i] = (i & 3) + 8*(i >> 2) + 4*h;
    }

    // ---- probe 3: C lane -> col map.  A=1, B=c+1 ----
    f32x16 r3 = __builtin_amdgcn_mfma_f32_32x32x16_bf16(pb1, pa2, zz, 0, 0, 0);
    int colstar;
    {
        float q = r3[0] * 0.0625f;
        int ci = (int)(q + 0.5f);
        bool ok3 = (fabsf(q - (float)ci) < 1e-3f) && ci >= 1 && ci <= 32;
        colstar = ci - 1;
        if (__ballot(!ok3) != 0ull) { sent += 4.0e10f; colstar = c; }
    }
    if (lane == 0 && sent > 0.f) atomicAdd(out, sent);

    const float INV = 0.2857142857142857f;   // 1/3.5
    float* slabW       = &lds[w][colstar][0];   // store: this lane's C column
    const float* slabR = &lds[w][c][0];         // read:  B operand column for this lane
    const int kb = (hf ? (1 - h) : h) * 8;      // delta: half-lane flip on B reads

    #pragma unroll 1
    for (int phase = 0; phase < 2; ++phase) {
        const float* Mp = (phase == 0 ? yhat : y) + ((size_t)b << 10);

        // ---- A-fragments of S (bf16 hi/lo); stage S to LDS as we go.
        // lds[w][c][k] = S[k][c] (row c == col c by symmetry) == T1 B-column c.
        bf16x8 Ah0, Al0, Ah1, Al1;
        {
            const float4* p = reinterpret_cast<const float4*>(Mp + c*32 + 8*h);
            float4 q0 = p[0], q1 = p[1];
            float fv[8] = {q0.x,q0.y,q0.z,q0.w, q1.x,q1.y,q1.z,q1.w};
            #pragma unroll
            for (int j = 0; j < 8; ++j) {
                int k = 8*h + j;
                float x = (fv[j] - ((k == c) ? 4.5f : 0.f)) * INV;
                unsigned hi = f2bfu(x);
                Ah0[j] = (short)hi; Al0[j] = (short)f2bfu(x - bf2f(hi));
                lds[w][c][k] = x;
            }
        }
        {
            const float4* p = reinterpret_cast<const float4*>(Mp + c*32 + 16 + 8*h);
            float4 q0 = p[0], q1 = p[1];
            float fv[8] = {q0.x,q0.y,q0.z,q0.w, q1.x,q1.y,q1.z,q1.w};
            #pragma unroll
            for (int j = 0; j < 8; ++j) {
                int k = 16 + 8*h + j;
                float x = (fv[j] - ((k == c) ? 4.5f : 0.f)) * INV;
                unsigned hi = f2bfu(x);
                Ah1[j] = (short)hi; Al1[j] = (short)f2bfu(x - bf2f(hi));
                lds[w][c][k] = x;
            }
        }

        // ---- V = T1 = S in C-space (LDS gather, same wave -> no barrier) ----
        float U[16], V[16], P[16];
        #pragma unroll
        for (int i = 0; i < 16; ++i) {
            float dg = (rws[i] == colstar) ? 1.f : 0.f;
            V[i] = lds[w][colstar][rws[i]];
            U[i] = dg;
            P[i] = fmaf(0.95518452f, V[i], 1.2986135f * dg); // c1*T1 + c0*I
        }

        // B-read with delta j-permutation (wave-uniform jm), hi/lo convert
        auto CVT8 = [&](const float* src, bf16x8& Bh, bf16x8& Bl) {
            float4 v0 = *reinterpret_cast<const float4*>(src);
            float4 v1 = *reinterpret_cast<const float4*>(src + 4);
            float f[8] = {v0.x,v0.y,v0.z,v0.w, v1.x,v1.y,v1.z,v1.w};
            if (jm == 0) {
                #pragma unroll
                for (int j = 0; j < 8; ++j) { float x = f[j];
                    unsigned hi = f2bfu(x); Bh[j]=(short)hi; Bl[j]=(short)f2bfu(x-bf2f(hi)); }
            } else if (jm == 1) {
                #pragma unroll
                for (int j = 0; j < 8; ++j) { float x = f[j ^ 4];
                    unsigned hi = f2bfu(x); Bh[j]=(short)hi; Bl[j]=(short)f2bfu(x-bf2f(hi)); }
            } else {
                #pragma unroll
                for (int j = 0; j < 8; ++j) { float x = f[7 - j];
                    unsigned hi = f2bfu(x); Bh[j]=(short)hi; Bl[j]=(short)f2bfu(x-bf2f(hi)); }
            }
        };

        // one Chebyshev step: LDS holds T_k; W held T_{k-1}; W <- 2*S*T_k - W
        auto STEP = [&](float coef, float (&W)[16], bool dostore) {
            bf16x8 Bh0, Bl0, Bh1, Bl1;
            CVT8(slabR + kb,      Bh0, Bl0);
            CVT8(slabR + 16 + kb, Bh1, Bl1);
            f32x16 a2 = zz;
            a2 = __builtin_amdgcn_mfma_f32_32x32x16_bf16(Ah0, Bh0, a2, 0,0,0);
            a2 = __builtin_amdgcn_mfma_f32_32x32x16_bf16(Ah0, Bl0, a2, 0,0,0);
            a2 = __builtin_amdgcn_mfma_f32_32x32x16_bf16(Al0, Bh0, a2, 0,0,0);
            a2 = __builtin_amdgcn_mfma_f32_32x32x16_bf16(Ah1, Bh1, a2, 0,0,0);
            a2 = __builtin_amdgcn_mfma_f32_32x32x16_bf16(Ah1, Bl1, a2, 0,0,0);
            a2 = __builtin_amdgcn_mfma_f32_32x32x16_bf16(Al1, Bh1, a2, 0,0,0);
            #pragma unroll
            for (int i = 0; i < 16; ++i) {
                float nw = 2.f * a2[i] - W[i];
                nw = fminf(fmaxf(nw, -64.f), 64.f);   // never binds when correct
                W[i] = nw;
                P[i] = fmaf(coef, nw, P[i]);
            }
            if (dostore) {
                #pragma unroll
                for (int i = 0; i < 16; ++i) slabW[rws[i]] = W[i];
            }
        };

        STEP(-0.22809412f, U, true);    // T2
        STEP( 0.07262391f, V, true);    // T3
        STEP(-0.02601347f, U, true);    // T4
        STEP( 0.00993906f, V, true);    // T5
        STEP(-0.00395568f, U, true);    // T6
        STEP( 0.00161931f, V, true);    // T7
        STEP(-0.00067670f, U, true);    // T8
        STEP( 0.00028728f, V, true);    // T9
        STEP(-0.00012348f, U, true);    // T10
        STEP( 0.00005361f, V, true);    // T11
        STEP(-0.00002347f, U, false);   // T12

        if (phase == 0) {
            #pragma unroll
            for (int i = 0; i < 16; ++i) pbuf[w][lane][i] = P[i];   // stash P_A in LDS
        } else {
            float s = 0.f;
            #pragma unroll
            for (int i = 0; i < 16; ++i) {
                float d = pbuf[w][lane][i] - P[i];
                s = fmaf(d, d, s);
            }
            #pragma unroll
            for (int m = 32; m >= 1; m >>= 1)
                s += bperm((lane ^ m) << 2, s);       // position-independent full sum
            if (lane == 0) bl[w] = valid * sqrtf(fmaxf(s, 0.f));
        }
    }

    __syncthreads();
    if (t == 0) {
        float sum = 0.f;
        #pragma unroll
        for (int i = 0; i < NW; ++i) sum += bl[i];
        atomicAdd(out, sum);
    }
}

extern "C" void kernel_launch(void* const* d_in, const int* in_sizes, int n_in,
                              void* d_out, int out_size, void* d_ws, size_t ws_size,
                              hipStream_t stream)
{
    const float* yhat = (const float*)d_in[0];
    const float* y    = (const float*)d_in[1];
    float* out = (float*)d_out;
    const int B = in_sizes[0] / 1024;   // 32*32 per matrix

    (void)hipMemsetAsync(out, 0, sizeof(float), stream);
    const int grid = (B + NW - 1) / NW;
    hipLaunchKernelGGL(geo_loss_mfma, dim3(grid), dim3(256), 0, stream,
                       yhat, y, out, B);
}

// Round 13
// 201.347 us; speedup vs baseline: 3.3032x; 1.3071x over previous
//
#include <hip/hip_runtime.h>
#include <hip/hip_bf16.h>
#include <math.h>

#define NW 4   // waves (=samples) per 256-thread block

typedef __attribute__((ext_vector_type(8)))  short bf16x8;
typedef __attribute__((ext_vector_type(16))) float f32x16;

__device__ __forceinline__ float bperm(int srcidx, float x) {
    return __int_as_float(__builtin_amdgcn_ds_bpermute(srcidx, __float_as_int(x)));
}
// f32 -> bf16 bits, RNE (manual, bit-deterministic: used by probes)
__device__ __forceinline__ unsigned f2bfu(float x) {
    unsigned u = __float_as_uint(x);
    return (u + 0x7fffu + ((u >> 16) & 1u)) >> 16;
}
__device__ __forceinline__ float bf2f(unsigned hb) { return __uint_as_float(hb << 16); }
// HW cast (v_cvt, RNE) for the hot paths
__device__ __forceinline__ unsigned short bfb(float x) {
    __hip_bfloat16 b = __float2bfloat16(x);
    unsigned short u;
    __builtin_memcpy(&u, &b, sizeof(u));
    return u;
}
__device__ __forceinline__ void split(float x, unsigned short& hb, unsigned short& lb) {
    hb = bfb(x);
    float lo = x - bf2f(hb);
    lb = bfb(lo);
}
// A-slot j <- source element delta_j(j); JM in {0:id, 1:j^4, 2:7-j} (compile-time)
template <int JM>
__device__ __forceinline__ bf16x8 pick(const unsigned short (&s)[8]) {
    bf16x8 r;
    #pragma unroll
    for (int j = 0; j < 8; ++j) {
        int idx = (JM == 0) ? j : (JM == 1 ? (j ^ 4) : (7 - j));
        r[j] = (short)s[idx];
    }
    return r;
}

// logm via deg-12 Chebyshev of log on [1,8]: S=(M-4.5I)/3.5, T_{k+1}=2ST_k-T_{k-1}.
// MFMA 32x32x16 bf16 hi/lo split. Layout facts discovered by 3 one-MFMA probes
// (proven R10/R11, absmax 0.0). R12: T_k stored in LDS as bf16 hi/lo PLANES ->
// B-frags are raw ds_read_b128 (zero per-step conversion); discovered delta folded
// into A-staging (one-time); quad b64 stores; PA in regs; 20.5 KB LDS.
__global__ __launch_bounds__(256, 1)
void geo_loss_mfma(const float* __restrict__ yhat, const float* __restrict__ y,
                   float* __restrict__ out, int B)
{
    __shared__ unsigned short hpl[NW][32][40];   // bf16 hi plane, [col][row], 80B stride
    __shared__ unsigned short lpl[NW][32][40];   // bf16 lo plane
    __shared__ float bl[NW];

    const int t    = threadIdx.x;
    const int w    = t >> 6;
    const int lane = t & 63;
    const int c    = lane & 31;
    const int h    = lane >> 5;

    int b = blockIdx.x * NW + w;
    const float valid = (b < B) ? 1.f : 0.f;
    if (b >= B) b = B - 1;

    const f32x16 zz = {0.f,0.f,0.f,0.f,0.f,0.f,0.f,0.f,0.f,0.f,0.f,0.f,0.f,0.f,0.f,0.f};
    float sent = 0.f;

    // ---- probe 1: relative A/B slot-labeling delta (6 hypotheses) ----
    bf16x8 pa;
    #pragma unroll
    for (int j = 0; j < 8; ++j) pa[j] = (short)f2bfu((float)(8*h + j + 1));
    int sel = -1;
    #pragma unroll
    for (int cand = 0; cand < 6; ++cand) {
        const int hfc = cand & 1, jmc = cand >> 1;
        bf16x8 pb;
        #pragma unroll
        for (int j = 0; j < 8; ++j) {
            int hh = hfc ? (1 - h) : h;
            int jj = (jmc == 0) ? j : (jmc == 1 ? (j ^ 4) : (7 - j));
            float lab = (float)(8*hh + jj + 1);
            pb[j] = (short)f2bfu(lab * lab);
        }
        f32x16 pr = __builtin_amdgcn_mfma_f32_32x32x16_bf16(pa, pb, zz, 0, 0, 0);
        if (sel < 0 && __ballot(pr[0] != 18496.f) == 0ull) sel = cand;  // sum m^3, m=1..16
    }
    if (sel < 0) { sent += 1.0e10f; sel = 0; }
    const int hf = sel & 1, jm = sel >> 1;

    // ---- probe 2: C (lane,reg) -> row map ----
    bf16x8 pa2, pb1;
    #pragma unroll
    for (int j = 0; j < 8; ++j) {
        pa2[j] = (short)f2bfu((float)(c + 1));
        pb1[j] = (short)f2bfu(1.f);
    }
    f32x16 r2 = __builtin_amdgcn_mfma_f32_32x32x16_bf16(pa2, pb1, zz, 0, 0, 0);
    int rws[16]; bool ok2 = true;
    #pragma unroll
    for (int i = 0; i < 16; ++i) {
        float q = r2[i] * 0.0625f;
        int ri = (int)(q + 0.5f);
        ok2 = ok2 && (fabsf(q - (float)ri) < 1e-3f) && ri >= 1 && ri <= 32;
        rws[i] = ri - 1;
    }
    if (__ballot(!ok2) != 0ull) {
        sent += 2.0e10f;
        #pragma unroll
        for (int i = 0; i < 16; ++i) rws[i] = (i & 3) + 8*(i >> 2) + 4*h;
    }

    // ---- probe 3: C lane -> col map ----
    f32x16 r3 = __builtin_amdgcn_mfma_f32_32x32x16_bf16(pb1, pa2, zz, 0, 0, 0);
    int colstar;
    {
        float q = r3[0] * 0.0625f;
        int ci = (int)(q + 0.5f);
        bool ok3 = (fabsf(q - (float)ci) < 1e-3f) && ci >= 1 && ci <= 32;
        colstar = ci - 1;
        if (__ballot(!ok3) != 0ull) { sent += 4.0e10f; colstar = c; }
    }
    if (lane == 0 && sent > 0.f) atomicAdd(out, sent);

    // quad-contiguity of discovered rows (enables b64 store fast path)
    bool qok = true;
    #pragma unroll
    for (int q = 0; q < 4; ++q)
        qok = qok && ((rws[4*q] & 3) == 0) && (rws[4*q+1] == rws[4*q]+1)
                  && (rws[4*q+2] == rws[4*q]+2) && (rws[4*q+3] == rws[4*q]+3);
    const bool allQuad = (__ballot(!qok) == 0ull);

    const float INV = 0.2857142857142857f;   // 1/3.5
    const int abase = 8 * (h ^ hf);          // delta hf folded into A-staging rows
    float PA[16];

    #pragma unroll 1
    for (int phase = 0; phase < 2; ++phase) {
        const float* Mp = (phase == 0 ? yhat : y) + ((size_t)b << 10);

        // ---- load S rows abase..abase+7 (+16), split hi/lo, stage to LDS ----
        unsigned short H0[8], L0[8], H1[8], L1[8];
        {
            const float4* p = reinterpret_cast<const float4*>(Mp + c*32 + abase);
            float4 q0 = p[0], q1 = p[1];
            float fv[8] = {q0.x,q0.y,q0.z,q0.w, q1.x,q1.y,q1.z,q1.w};
            #pragma unroll
            for (int m = 0; m < 8; ++m) {
                int k = abase + m;
                float x = (fv[m] - ((k == c) ? 4.5f : 0.f)) * INV;
                split(x, H0[m], L0[m]);
            }
        }
        {
            const float4* p = reinterpret_cast<const float4*>(Mp + c*32 + 16 + abase);
            float4 q0 = p[0], q1 = p[1];
            float fv[8] = {q0.x,q0.y,q0.z,q0.w, q1.x,q1.y,q1.z,q1.w};
            #pragma unroll
            for (int m = 0; m < 8; ++m) {
                int k = 16 + abase + m;
                float x = (fv[m] - ((k == c) ? 4.5f : 0.f)) * INV;
                split(x, H1[m], L1[m]);
            }
        }
        // stage T1 = S to LDS planes (natural row order), 16B writes
        auto packw = [](const unsigned short (&s)[8]) {
            return make_uint4((unsigned)s[0] | ((unsigned)s[1] << 16),
                              (unsigned)s[2] | ((unsigned)s[3] << 16),
                              (unsigned)s[4] | ((unsigned)s[5] << 16),
                              (unsigned)s[6] | ((unsigned)s[7] << 16));
        };
        *reinterpret_cast<uint4*>(&hpl[w][c][abase])      = packw(H0);
        *reinterpret_cast<uint4*>(&lpl[w][c][abase])      = packw(L0);
        *reinterpret_cast<uint4*>(&hpl[w][c][16 + abase]) = packw(H1);
        *reinterpret_cast<uint4*>(&lpl[w][c][16 + abase]) = packw(L1);

        // ---- A-frags with delta-j permutation (compile-time per branch) ----
        bf16x8 Ah0, Al0, Ah1, Al1;
        if (jm == 0) {
            Ah0 = pick<0>(H0); Al0 = pick<0>(L0); Ah1 = pick<0>(H1); Al1 = pick<0>(L1);
        } else if (jm == 1) {
            Ah0 = pick<1>(H0); Al0 = pick<1>(L0); Ah1 = pick<1>(H1); Al1 = pick<1>(L1);
        } else {
            Ah0 = pick<2>(H0); Al0 = pick<2>(L0); Ah1 = pick<2>(H1); Al1 = pick<2>(L1);
        }

        // ---- V = T1 in C-space (hi+lo from LDS, same wave -> no barrier) ----
        float U[16], V[16], P[16];
        #pragma unroll
        for (int i = 0; i < 16; ++i) {
            float dg = (rws[i] == colstar) ? 1.f : 0.f;
            float tv = bf2f(hpl[w][colstar][rws[i]]) + bf2f(lpl[w][colstar][rws[i]]);
            V[i] = tv; U[i] = dg;
            P[i] = fmaf(0.95518452f, tv, 1.2986135f * dg);   // c1*T1 + c0*I
        }

        // one Chebyshev step: LDS holds T_k (hi/lo); W held T_{k-1}; W <- 2*S*T_k - W
        auto STEP = [&](float coef, float (&W)[16], bool dostore) {
            bf16x8 Bh0 = *reinterpret_cast<const bf16x8*>(&hpl[w][c][8*h]);
            bf16x8 Bl0 = *reinterpret_cast<const bf16x8*>(&lpl[w][c][8*h]);
            bf16x8 Bh1 = *reinterpret_cast<const bf16x8*>(&hpl[w][c][16 + 8*h]);
            bf16x8 Bl1 = *reinterpret_cast<const bf16x8*>(&lpl[w][c][16 + 8*h]);
            f32x16 a2 = zz;
            a2 = __builtin_amdgcn_mfma_f32_32x32x16_bf16(Ah0, Bh0, a2, 0,0,0);
            a2 = __builtin_amdgcn_mfma_f32_32x32x16_bf16(Ah0, Bl0, a2, 0,0,0);
            a2 = __builtin_amdgcn_mfma_f32_32x32x16_bf16(Al0, Bh0, a2, 0,0,0);
            a2 = __builtin_amdgcn_mfma_f32_32x32x16_bf16(Ah1, Bh1, a2, 0,0,0);
            a2 = __builtin_amdgcn_mfma_f32_32x32x16_bf16(Ah1, Bl1, a2, 0,0,0);
            a2 = __builtin_amdgcn_mfma_f32_32x32x16_bf16(Al1, Bh1, a2, 0,0,0);
            #pragma unroll
            for (int i = 0; i < 16; ++i) {
                float nw = fmaf(2.f, a2[i], -W[i]);
                W[i] = nw;
                P[i] = fmaf(coef, nw, P[i]);
            }
            if (dostore) {
                if (allQuad) {
                    #pragma unroll
                    for (int q = 0; q < 4; ++q) {
                        int rq = rws[4*q];
                        unsigned short hb[4], lb[4];
                        #pragma unroll
                        for (int e = 0; e < 4; ++e) split(W[4*q+e], hb[e], lb[e]);
                        *reinterpret_cast<uint2*>(&hpl[w][colstar][rq]) =
                            make_uint2((unsigned)hb[0] | ((unsigned)hb[1] << 16),
                                       (unsigned)hb[2] | ((unsigned)hb[3] << 16));
                        *reinterpret_cast<uint2*>(&lpl[w][colstar][rq]) =
                            make_uint2((unsigned)lb[0] | ((unsigned)lb[1] << 16),
                                       (unsigned)lb[2] | ((unsigned)lb[3] << 16));
                    }
                } else {
                    #pragma unroll
                    for (int i = 0; i < 16; ++i) {
                        unsigned short hb, lb; split(W[i], hb, lb);
                        hpl[w][colstar][rws[i]] = hb;
                        lpl[w][colstar][rws[i]] = lb;
                    }
                }
            }
        };

        STEP(-0.22809412f, U, true);    // T2
        STEP( 0.07262391f, V, true);    // T3
        STEP(-0.02601347f, U, true);    // T4
        STEP( 0.00993906f, V, true);    // T5
        STEP(-0.00395568f, U, true);    // T6
        STEP( 0.00161931f, V, true);    // T7
        STEP(-0.00067670f, U, true);    // T8
        STEP( 0.00028728f, V, true);    // T9
        STEP(-0.00012348f, U, true);    // T10
        STEP( 0.00005361f, V, true);    // T11
        STEP(-0.00002347f, U, false);   // T12

        if (phase == 0) {
            #pragma unroll
            for (int i = 0; i < 16; ++i) PA[i] = P[i];
        } else {
            float s = 0.f;
            #pragma unroll
            for (int i = 0; i < 16; ++i) { float d = PA[i] - P[i]; s = fmaf(d, d, s); }
            #pragma unroll
            for (int m = 32; m >= 1; m >>= 1)
                s += bperm((lane ^ m) << 2, s);       // position-independent full sum
            if (lane == 0) bl[w] = valid * sqrtf(fmaxf(s, 0.f));
        }
    }

    __syncthreads();
    if (t == 0) {
        float sum = 0.f;
        #pragma unroll
        for (int i = 0; i < NW; ++i) sum += bl[i];
        atomicAdd(out, sum);
    }
}

extern "C" void kernel_launch(void* const* d_in, const int* in_sizes, int n_in,
                              void* d_out, int out_size, void* d_ws, size_t ws_size,
                              hipStream_t stream)
{
    const float* yhat = (const float*)d_in[0];
    const float* y    = (const float*)d_in[1];
    float* out = (float*)d_out;
    const int B = in_sizes[0] / 1024;   // 32*32 per matrix

    (void)hipMemsetAsync(out, 0, sizeof(float), stream);
    const int grid = (B + NW - 1) / NW;
    hipLaunchKernelGGL(geo_loss_mfma, dim3(grid), dim3(256), 0, stream,
                       yhat, y, out, B);
}